// Round 1
// baseline (392.809 us; speedup 1.0000x reference)
//
#include <hip/hip_runtime.h>
#include <hip/hip_fp16.h>

#define BATCH 65536
#define KDIM  784
#define HID   512
#define NTK   25     // K-tiles of 32 (784 = 24*32+16, last tile zero-padded)
#define BM    64

typedef float    f32x4 __attribute__((ext_vector_type(4)));
typedef _Float16 f16x8 __attribute__((ext_vector_type(8)));
typedef _Float16 f16x4 __attribute__((ext_vector_type(4)));

__device__ __forceinline__ void gload_lds16(const void* g, void* l) {
  __builtin_amdgcn_global_load_lds((const __attribute__((address_space(1))) void*)g,
                                   (__attribute__((address_space(3))) void*)l, 16, 0, 0);
}

// W1 (784x512 fp32) -> ws: fp16, transposed-per-column-frag layout, K-tiled [net][25][512][32],
// zero-padded to k=800, 16B-slot XOR-swizzled by (n&3) so the main kernel's linear
// global_load_lds + swizzled ds_read_b128 is bank-conflict-free (2-way max).
__global__ void prep_w1_kernel(const float* __restrict__ W1_0,
                               const float* __restrict__ W1_1,
                               _Float16* __restrict__ wsB) {
  int i = blockIdx.x * 256 + threadIdx.x;       // [0, 2*800*512)
  if (i >= 2 * 800 * 512) return;
  int net = i / (800 * 512);
  int rem = i - net * (800 * 512);
  int k = rem >> 9;
  int n = rem & 511;
  const float* W = net ? W1_1 : W1_0;
  float v = (k < KDIM) ? W[k * 512 + n] : 0.f;
  int kt = k >> 5, kk = k & 31, slot = kk >> 3, e = kk & 7;
  int dst = (((net * NTK + kt) * 512 + n) << 5) + ((slot ^ (n & 3)) << 3) + e;
  wsB[dst] = (_Float16)v;
}

// W2 (512x10 fp32) -> ws: fp16 W2^T padded to 16 cols (zeros), [net][16][512],
// 16B-slot XOR-swizzled by (j&7).
__global__ void prep_w2_kernel(const float* __restrict__ W2_0,
                               const float* __restrict__ W2_1,
                               _Float16* __restrict__ wsW2) {
  int i = blockIdx.x * 256 + threadIdx.x;       // [0, 2*16*512)
  if (i >= 2 * 16 * 512) return;
  int net = i >> 13;
  int rem = i & 8191;
  int j = rem >> 9;
  int k = rem & 511;
  const float* W = net ? W2_1 : W2_0;
  float v = (j < 10) ? W[k * 10 + j] : 0.f;
  int slot = k >> 3, e = k & 7;
  wsW2[(net << 13) + (j << 9) + ((slot ^ (j & 7)) << 3) + e] = (_Float16)v;
}

__launch_bounds__(256, 2)
__global__ void fused_mlp_kernel(const float* __restrict__ x,
                                 const float* __restrict__ b1_0,
                                 const float* __restrict__ b2_0,
                                 const float* __restrict__ b1_1,
                                 const float* __restrict__ b2_1,
                                 const _Float16* __restrict__ wsB,
                                 const _Float16* __restrict__ wsW2,
                                 float* __restrict__ out) {
  // Transient union: K-loop staging As(4096)+Bs(32768) = 36864 B
  //                  post-K:        hbuf(16384)+W2s(16384) = 32768 B
  //                  final:         outb(64*19*4 = 4864 B)
  __shared__ __attribute__((aligned(16))) char ldsu[36864];
  __shared__ float p0buf[BM * 17];   // stride 17: odd stride kills conv-phase bank conflicts
  __shared__ float p1buf[BM * 17];

  char* AsB = ldsu;
  char* BsB = ldsu + 4096;
  char* hB  = ldsu;
  char* W2B = ldsu + 16384;
  float* outb = (float*)ldsu;

  const int t    = threadIdx.x;
  const int lane = t & 63;
  const int wid  = t >> 6;
  const int l15  = lane & 15;
  const int l4   = lane >> 4;
  const int row0 = blockIdx.x * BM;

  const f32x4 zero4 = {0.f, 0.f, 0.f, 0.f};

  for (int net = 0; net < 2; ++net) {
    const float* xb = x + (size_t)net * BATCH * KDIM + (size_t)row0 * KDIM;
    const _Float16* wtile = wsB + (size_t)net * NTK * HID * 32;
    const float* b1 = net ? b1_1 : b1_0;
    const float* b2 = net ? b2_1 : b2_0;
    float* pb = net ? p1buf : p0buf;

    f32x4 acc[4][8];
#pragma unroll
    for (int rf = 0; rf < 4; ++rf)
#pragma unroll
      for (int cf = 0; cf < 8; ++cf) acc[rf][cf] = zero4;

    // ---- GEMM1 K-loop: h(64x512) = x(64x784) @ W1 ----
    for (int kt = 0; kt < NTK; ++kt) {
      // stage A: fp32 x -> f16 LDS (XOR-swizzled 16B slots)
#pragma unroll
      for (int ci = 0; ci < 2; ++ci) {
        int c = t + ci * 256;         // 512 chunks of 4 floats = 64 rows x 32 k
        int row = c >> 3;
        int kk = (c & 7) << 2;
        int kg = (kt << 5) + kk;
        f32x4 v = zero4;
        if (kg < KDIM) v = *(const f32x4*)(xb + (size_t)row * KDIM + kg);
        f16x4 hv;
        hv[0] = (_Float16)v[0]; hv[1] = (_Float16)v[1];
        hv[2] = (_Float16)v[2]; hv[3] = (_Float16)v[3];
        int slot = kk >> 3;
        *(f16x4*)(AsB + (row << 6) + ((slot ^ (row & 3)) << 4) + ((kk & 7) << 1)) = hv;
      }
      // stage B: linear 32 KB global_load_lds (swizzle pre-baked in ws)
      {
        const char* gsrc = (const char*)(wtile + (size_t)kt * HID * 32);
#pragma unroll
        for (int i = 0; i < 8; ++i) {
          int chunk = (wid << 3) + i;
          gload_lds16(gsrc + (chunk << 10) + (lane << 4), BsB + (chunk << 10));
        }
      }
      __syncthreads();

      f16x8 bfr[8];
#pragma unroll
      for (int cf = 0; cf < 8; ++cf) {
        int n = (wid << 7) + (cf << 4) + l15;
        bfr[cf] = *(f16x8*)(BsB + (n << 6) + ((l4 ^ (n & 3)) << 4));
      }
#pragma unroll
      for (int rf = 0; rf < 4; ++rf) {
        int row = (rf << 4) + l15;
        f16x8 af = *(f16x8*)(AsB + (row << 6) + ((l4 ^ (row & 3)) << 4));
#pragma unroll
        for (int cf = 0; cf < 8; ++cf)
          acc[rf][cf] = __builtin_amdgcn_mfma_f32_16x16x32_f16(af, bfr[cf], acc[rf][cf], 0, 0, 0);
      }
      __syncthreads();
    }

    // ---- bias + relu (acc -> h in registers) ----
#pragma unroll
    for (int cf = 0; cf < 8; ++cf) {
      float bv = b1[(wid << 7) + (cf << 4) + l15];
#pragma unroll
      for (int rf = 0; rf < 4; ++rf)
#pragma unroll
        for (int j = 0; j < 4; ++j)
          acc[rf][cf][j] = fmaxf(acc[rf][cf][j] + bv, 0.f);
    }

    // ---- load W2^T (16 KB) into LDS (region is free after K-loop barrier) ----
    {
      const char* gsrc = (const char*)(wsW2 + (net << 13));
#pragma unroll
      for (int i = 0; i < 4; ++i) {
        int chunk = (wid << 2) + i;
        gload_lds16(gsrc + (chunk << 10) + (lane << 4), W2B + (chunk << 10));
      }
    }

    // ---- GEMM2: logits(64x16) = h(64x512) @ W2pad, q-round-robin through 16KB hbuf ----
    f32x4 lacc = zero4;
#pragma unroll
    for (int q = 0; q < 4; ++q) {
      if (wid == q) {                 // wave q publishes its 64x128 h chunk
#pragma unroll
        for (int rf = 0; rf < 4; ++rf)
#pragma unroll
          for (int cf = 0; cf < 8; ++cf) {
            int coll = (cf << 4) + l15;
            int slot = coll >> 3;
            int wb = (coll & 7) << 1;
#pragma unroll
            for (int j = 0; j < 4; ++j) {
              int row = (rf << 4) + (l4 << 2) + j;
              *(_Float16*)(hB + (row << 8) + ((slot ^ (row & 7)) << 4) + wb) =
                  (_Float16)acc[rf][cf][j];
            }
          }
      }
      __syncthreads();                // hbuf ready (also drains W2 load on q=0)
#pragma unroll
      for (int kt2 = 0; kt2 < 4; ++kt2) {
        int row = (wid << 4) + l15;   // wave w owns output rows w*16..w*16+15
        int aslot = (kt2 << 2) + l4;
        f16x8 af = *(f16x8*)(hB + (row << 8) + ((aslot ^ (row & 7)) << 4));
        int s2 = (q << 4) + (kt2 << 2) + l4;
        f16x8 bf = *(f16x8*)(W2B + (l15 << 10) + ((s2 ^ (l15 & 7)) << 4));
        lacc = __builtin_amdgcn_mfma_f32_16x16x32_f16(af, bf, lacc, 0, 0, 0);
      }
      __syncthreads();                // all reads done before next q overwrites hbuf
    }

    // ---- bias2 + softmax (cols spread over l15; butterfly over 16-lane groups) ----
    float b2v = (l15 < 10) ? b2[l15] : 0.f;
    float lg[4], mx[4], ev[4], sm[4];
#pragma unroll
    for (int j = 0; j < 4; ++j) lg[j] = (l15 < 10) ? (lacc[j] + b2v) : -1e30f;
#pragma unroll
    for (int j = 0; j < 4; ++j) mx[j] = lg[j];
#pragma unroll
    for (int m = 1; m < 16; m <<= 1)
#pragma unroll
      for (int j = 0; j < 4; ++j) mx[j] = fmaxf(mx[j], __shfl_xor(mx[j], m));
#pragma unroll
    for (int j = 0; j < 4; ++j) { ev[j] = (l15 < 10) ? __expf(lg[j] - mx[j]) : 0.f; sm[j] = ev[j]; }
#pragma unroll
    for (int m = 1; m < 16; m <<= 1)
#pragma unroll
      for (int j = 0; j < 4; ++j) sm[j] += __shfl_xor(sm[j], m);
#pragma unroll
    for (int j = 0; j < 4; ++j) {
      int row = (wid << 4) + (l4 << 2) + j;
      pb[row * 17 + l15] = ev[j] / sm[j];
    }
  } // net

  __syncthreads();   // p0/p1 visible; hbuf reads all complete

  // ---- out[n][s] = sum_{a+c=s} p0[n][a] * p1[n][c] ----
  {
    int r = t & 63;
    int sq = t >> 6;
#pragma unroll
    for (int si = 0; si < 5; ++si) {
      int s = sq * 5 + si;
      if (s < 19) {
        int alo = (s > 9) ? (s - 9) : 0;
        int ahi = (s < 9) ? s : 9;
        float a = 0.f;
        for (int aa = alo; aa <= ahi; ++aa)
          a += p0buf[r * 17 + aa] * p1buf[r * 17 + (s - aa)];
        outb[r * 19 + s] = a;
      }
    }
  }
  __syncthreads();
  {
    float* og = out + (size_t)row0 * 19;
    for (int i = t; i < BM * 19; i += 256) og[i] = outb[i];
  }
}

extern "C" void kernel_launch(void* const* d_in, const int* in_sizes, int n_in,
                              void* d_out, int out_size, void* d_ws, size_t ws_size,
                              hipStream_t stream) {
  (void)in_sizes; (void)n_in; (void)out_size; (void)ws_size;
  const float* x    = (const float*)d_in[0];
  const float* W1_0 = (const float*)d_in[1];
  const float* b1_0 = (const float*)d_in[2];
  const float* W2_0 = (const float*)d_in[3];
  const float* b2_0 = (const float*)d_in[4];
  const float* W1_1 = (const float*)d_in[5];
  const float* b1_1 = (const float*)d_in[6];
  const float* W2_1 = (const float*)d_in[7];
  const float* b2_1 = (const float*)d_in[8];
  float* out = (float*)d_out;

  _Float16* wsB  = (_Float16*)d_ws;                 // 2*25*512*32 = 819200 f16 = 1.6 MB
  _Float16* wsW2 = wsB + 2 * NTK * HID * 32;        // 2*16*512   =  16384 f16 = 32 KB

  hipLaunchKernelGGL(prep_w1_kernel, dim3(3200), dim3(256), 0, stream, W1_0, W1_1, wsB);
  hipLaunchKernelGGL(prep_w2_kernel, dim3(64), dim3(256), 0, stream, W2_0, W2_1, wsW2);
  hipLaunchKernelGGL(fused_mlp_kernel, dim3(BATCH / BM), dim3(256), 0, stream,
                     x, b1_0, b2_0, b1_1, b2_1, wsB, wsW2, out);
}

// Round 2
// 231.252 us; speedup vs baseline: 1.6986x; 1.6986x over previous
//
#include <hip/hip_runtime.h>
#include <hip/hip_fp16.h>

#define BATCH 65536
#define KDIM  784
#define HID   512
#define NTK   25     // K-tiles of 32 (784 = 24*32+16, last tile zero-padded)
#define BM    64

typedef float    f32x4 __attribute__((ext_vector_type(4)));
typedef _Float16 f16x8 __attribute__((ext_vector_type(8)));
typedef _Float16 f16x4 __attribute__((ext_vector_type(4)));

__device__ __forceinline__ void gload_lds16(const void* g, void* l) {
  __builtin_amdgcn_global_load_lds((const __attribute__((address_space(1))) void*)g,
                                   (__attribute__((address_space(3))) void*)l, 16, 0, 0);
}

// W1 (784x512 fp32) -> ws: fp16 in exact A-fragment order [net][kt][hid][32],
// zero-padded to k=800. Linear (no swizzle): consumed global->reg.
__global__ void prep_w1_kernel(const float* __restrict__ W1_0,
                               const float* __restrict__ W1_1,
                               _Float16* __restrict__ wsB) {
  int i = blockIdx.x * 256 + threadIdx.x;       // [0, 2*800*512)
  if (i >= 2 * 800 * 512) return;
  int net = i / (800 * 512);
  int rem = i - net * (800 * 512);
  int k = rem >> 9;        // 0..799
  int hid = rem & 511;
  const float* W = net ? W1_1 : W1_0;
  float v = (k < KDIM) ? W[k * 512 + hid] : 0.f;
  int kt = k >> 5, kk = k & 31;
  wsB[(((size_t)(net * NTK + kt) * HID + hid) << 5) + kk] = (_Float16)v;
}

// W2 (512x10 fp32) -> ws: fp16 W2^T padded to 16 rows, [net][16][512], linear.
__global__ void prep_w2_kernel(const float* __restrict__ W2_0,
                               const float* __restrict__ W2_1,
                               _Float16* __restrict__ wsW2) {
  int i = blockIdx.x * 256 + threadIdx.x;       // [0, 2*16*512)
  if (i >= 2 * 16 * 512) return;
  int net = i >> 13;
  int rem = i & 8191;
  int li = rem >> 9;       // logit row 0..15
  int k = rem & 511;
  const float* W = net ? W2_1 : W2_0;
  wsW2[i] = (_Float16)((li < 10) ? W[k * 10 + li] : 0.f);
}

__launch_bounds__(256, 2)
__global__ void fused_mlp_kernel(const float* __restrict__ x,
                                 const float* __restrict__ b1_0,
                                 const float* __restrict__ b2_0,
                                 const float* __restrict__ b1_1,
                                 const float* __restrict__ b2_1,
                                 const _Float16* __restrict__ wsB,
                                 const _Float16* __restrict__ wsW2,
                                 float* __restrict__ out) {
  // hreg: K-loop = x double-buffer (2 x 8KB fp32, rows 64 x 128B, 16B-slot swizzle)
  //       post-K = h[64][512] f16 (64KB, 16B-slot swizzle), then outb.
  __shared__ __attribute__((aligned(16))) char hreg[65536];
  __shared__ float pbuf[2][BM * 17];   // stride 17 kills conv-phase conflicts

  const int t    = threadIdx.x;
  const int lane = t & 63;
  const int wid  = t >> 6;
  const int l15  = lane & 15;
  const int l4   = lane >> 4;
  const int hid0 = wid << 7;            // wave owns hid cols [hid0, hid0+128)
  const int row0 = blockIdx.x * BM;

  // staging geometry: chunk c covers rows c*8..c*8+7; lane l -> row c*8+(l>>3), slot l&7
  const int sc0   = wid << 1;
  const int srowl = lane >> 3;
  const int sl7   = lane & 7;

  for (int net = 0; net < 2; ++net) {
    const float* xb = x + (size_t)net * BATCH * KDIM + (size_t)row0 * KDIM;
    const _Float16* wnet = wsB + (size_t)net * NTK * HID * 32;
    const float* b1 = net ? b1_1 : b1_0;
    const float* b2 = net ? b2_1 : b2_0;

    f32x4 acc[8][4];
#pragma unroll
    for (int rf = 0; rf < 8; ++rf)
#pragma unroll
      for (int nf = 0; nf < 4; ++nf) acc[rf][nf] = (f32x4){0.f, 0.f, 0.f, 0.f};

    // ---- prologue: stage x k-tile 0 into buf 0 (pre-swizzled source) ----
#pragma unroll
    for (int i = 0; i < 2; ++i) {
      int c = sc0 + i;
      int srow = (c << 3) + srowl;
      int kc = sl7 ^ (srow & 7);
      int kg = kc << 2;                  // kt=0: always < 784
      gload_lds16(xb + (size_t)srow * KDIM + kg, hreg + (c << 10));
    }
    __syncthreads();

    // ---- GEMM1 K-loop: h^T(512x64) = W1^T @ x^T, one barrier per kt ----
    int bufb = 0;
    for (int kt = 0; kt < NTK; ++kt) {
      // A-frags: W1 global->reg (L2-resident, exact fragment order)
      f16x8 bw[8];
      const _Float16* wk = wnet + ((size_t)kt * HID << 5);
#pragma unroll
      for (int rf = 0; rf < 8; ++rf)
        bw[rf] = *(const f16x8*)(wk + ((hid0 + (rf << 4) + l15) << 5) + (l4 << 3));

      // stage next x tile into other buffer (hidden under ds_read+cvt+MFMA)
      if (kt < NTK - 1) {
#pragma unroll
        for (int i = 0; i < 2; ++i) {
          int c = sc0 + i;
          int srow = (c << 3) + srowl;
          int kc = sl7 ^ (srow & 7);
          int kg = ((kt + 1) << 5) + (kc << 2);
          if (kg >= KDIM) kg = 0;        // tail: garbage row-0 data x 0-padded W1 = 0
          gload_lds16(xb + (size_t)srow * KDIM + kg, hreg + (bufb ^ 8192) + (c << 10));
        }
      }

      // B-frags: x from LDS (fp32, swizzled slots) -> cvt f16
      f16x8 bx[4];
#pragma unroll
      for (int nf = 0; nf < 4; ++nf) {
        int row = (nf << 4) + l15;
#pragma unroll
        for (int h = 0; h < 2; ++h) {
          int sl = ((l4 << 1) + h) ^ (row & 7);
          f32x4 v = *(const f32x4*)(hreg + bufb + (row << 7) + (sl << 4));
          bx[nf][h * 4 + 0] = (_Float16)v[0];
          bx[nf][h * 4 + 1] = (_Float16)v[1];
          bx[nf][h * 4 + 2] = (_Float16)v[2];
          bx[nf][h * 4 + 3] = (_Float16)v[3];
        }
      }

#pragma unroll
      for (int rf = 0; rf < 8; ++rf)
#pragma unroll
        for (int nf = 0; nf < 4; ++nf)
          acc[rf][nf] = __builtin_amdgcn_mfma_f32_16x16x32_f16(bw[rf], bx[nf], acc[rf][nf], 0, 0, 0);

      __syncthreads();   // drains this iter's gload_lds; gates buffer swap
      bufb ^= 8192;
    }

    // ---- bias+relu, all waves publish h (f16, swizzled 16B slots) in parallel ----
    // D layout: col=l15=batch(within nf), row=hid offset l4*4+j -> 4 consecutive hid = f16x4
#pragma unroll
    for (int rf = 0; rf < 8; ++rf) {
      f32x4 bv = *(const f32x4*)(b1 + hid0 + (rf << 4) + (l4 << 2));
#pragma unroll
      for (int nf = 0; nf < 4; ++nf) {
        f16x4 hv;
#pragma unroll
        for (int j = 0; j < 4; ++j)
          hv[j] = (_Float16)fmaxf(acc[rf][nf][j] + bv[j], 0.f);
        int row = (nf << 4) + l15;
        int slot = (wid << 4) + (rf << 1) + (l4 >> 1);   // = hid/8
        *(f16x4*)(hreg + (row << 10) + ((slot ^ (row & 7)) << 4) + ((l4 & 1) << 3)) = hv;
      }
    }
    __syncthreads();

    // ---- GEMM2: logits^T(16x16) per wave, full k=512; W2^T frags global->reg ----
    f32x4 l2 = {0.f, 0.f, 0.f, 0.f};
    {
      const _Float16* w2n = wsW2 + (((net << 4) + l15) << 9);  // A row i = l15 (logit)
      int row = (wid << 4) + l15;                              // B col j = batch row
#pragma unroll
      for (int kk = 0; kk < 16; ++kk) {
        f16x8 aw = *(const f16x8*)(w2n + (kk << 5) + (l4 << 3));
        int sl = ((kk << 2) + l4) ^ (row & 7);
        f16x8 bh = *(const f16x8*)(hreg + (row << 10) + (sl << 4));
        l2 = __builtin_amdgcn_mfma_f32_16x16x32_f16(aw, bh, l2, 0, 0, 0);
      }
    }

    // ---- softmax: lane holds logits cls0..cls0+3 of batch row wid*16+l15 ----
    int cls0 = l4 << 2;
    float lg[4];
#pragma unroll
    for (int j = 0; j < 4; ++j) {
      int c = cls0 + j;
      lg[j] = (c < 10) ? (l2[j] + b2[c]) : -1e30f;
    }
    float mx = fmaxf(fmaxf(lg[0], lg[1]), fmaxf(lg[2], lg[3]));
    mx = fmaxf(mx, __shfl_xor(mx, 16));
    mx = fmaxf(mx, __shfl_xor(mx, 32));
    float ev[4], s = 0.f;
#pragma unroll
    for (int j = 0; j < 4; ++j) {
      ev[j] = (cls0 + j < 10) ? __expf(lg[j] - mx) : 0.f;
      s += ev[j];
    }
    s += __shfl_xor(s, 16);
    s += __shfl_xor(s, 32);
    float inv = 1.f / s;
#pragma unroll
    for (int j = 0; j < 4; ++j) {
      int c = cls0 + j;
      if (c < 10) pbuf[net][((wid << 4) + l15) * 17 + c] = ev[j] * inv;
    }
    __syncthreads();   // p visible; hreg reads done before next net re-stages
  } // net

  // ---- out[n][s] = sum_{a+c=s} p0[n][a] * p1[n][c] ----
  float* outb = (float*)hreg;
  {
    int r = t & 63;
    int sq = t >> 6;
#pragma unroll
    for (int si = 0; si < 5; ++si) {
      int s = sq * 5 + si;
      if (s < 19) {
        int alo = (s > 9) ? (s - 9) : 0;
        int ahi = (s < 9) ? s : 9;
        float a = 0.f;
        for (int aa = alo; aa <= ahi; ++aa)
          a += pbuf[0][r * 17 + aa] * pbuf[1][r * 17 + (s - aa)];
        outb[r * 19 + s] = a;
      }
    }
  }
  __syncthreads();
  {
    float* og = out + (size_t)row0 * 19;
    for (int i = t; i < BM * 19; i += 256) og[i] = outb[i];
  }
}

extern "C" void kernel_launch(void* const* d_in, const int* in_sizes, int n_in,
                              void* d_out, int out_size, void* d_ws, size_t ws_size,
                              hipStream_t stream) {
  (void)in_sizes; (void)n_in; (void)out_size; (void)ws_size;
  const float* x    = (const float*)d_in[0];
  const float* W1_0 = (const float*)d_in[1];
  const float* b1_0 = (const float*)d_in[2];
  const float* W2_0 = (const float*)d_in[3];
  const float* b2_0 = (const float*)d_in[4];
  const float* W1_1 = (const float*)d_in[5];
  const float* b1_1 = (const float*)d_in[6];
  const float* W2_1 = (const float*)d_in[7];
  const float* b2_1 = (const float*)d_in[8];
  float* out = (float*)d_out;

  _Float16* wsB  = (_Float16*)d_ws;                 // 2*25*512*32 = 819200 f16 = 1.6 MB
  _Float16* wsW2 = wsB + 2 * NTK * HID * 32;        // 2*16*512   =  16384 f16 = 32 KB

  hipLaunchKernelGGL(prep_w1_kernel, dim3(3200), dim3(256), 0, stream, W1_0, W1_1, wsB);
  hipLaunchKernelGGL(prep_w2_kernel, dim3(64), dim3(256), 0, stream, W2_0, W2_1, wsW2);
  hipLaunchKernelGGL(fused_mlp_kernel, dim3(BATCH / BM), dim3(256), 0, stream,
                     x, b1_0, b2_0, b1_1, b2_1, wsB, wsW2, out);
}